// Round 10
// baseline (110.796 us; speedup 1.0000x reference)
//
#include <hip/hip_runtime.h>

// Chamfer loss: pred (8,4096,3) f32, target (8,4096,3) f32 -> scalar f32.
// dist = |q|^2 + (|t|^2 - 2 q.t). Packed inner loop: per 2 targets per query
// 3 v_pk_fma_f32 + 1 v_min3_f32. LDS tile pair-packed: pairA=(x0,x1,y0,y1),
// pairB=(z0,z1,w0,w1) with w=|t|^2; |q|^2 added after the cross-slice min.
//
// Round-10: QPT 8->16 (NQG=8, NSL=64). Rationale: R7~R8 neutrality pinned the
// main kernel at the LDS issue bound (~10us: 2 broadcast ds_read_b128 per
// 2 targets per wave). Doubling queries/thread halves ds_read issues/wave
// (LDS ~5.1us) while aggregate VALU stays ~6.8us. 2-node structure (R9
// lesson: fenceless single-node last-block trigger is unsound with an
// uninitialized counter — reverted).

typedef float v2f __attribute__((ext_vector_type(2)));

#define BATCH 8
#define NPTS  4096
#define TPB   512
#define QPT   16                      // queries per thread
#define NQG   8                       // query groups per block
#define QB    (NQG * QPT)             // 128 queries per block
#define NSL   64                      // target slices per block
#define NBLK  (2 * BATCH * (NPTS / QB))  // 512 blocks
#define PHPTS 2048                    // targets staged per phase
#define NPAIR (PHPTS / 2)             // 1024 pairs per phase
#define SPAIR (NPAIR / NSL)           // 16 pairs per slice per phase

// per pair j: 2 uniform ds_read_b128 + per query 3 pk_fma + 1 min3.
#define INNER_LOOP(PA, PB)                                                    \
    _Pragma("unroll 4")                                                       \
    for (int j = 0; j < SPAIR; ++j) {                                         \
        float4 A = (PA)[j];                                                   \
        float4 B = (PB)[j];                                                   \
        v2f xx = {A.x, A.y}, yy = {A.z, A.w};                                 \
        v2f zz = {B.x, B.y}, ww = {B.z, B.w};                                 \
        _Pragma("unroll")                                                     \
        for (int k = 0; k < QPT; ++k) {                                       \
            v2f d = __builtin_elementwise_fma(az2[k], zz, ww);                \
            d = __builtin_elementwise_fma(ay2[k], yy, d);                     \
            d = __builtin_elementwise_fma(ax2[k], xx, d);                     \
            mn[k] = fminf(fminf(d.x, d.y), mn[k]);    /* v_min3_f32 */        \
        }                                                                     \
    }

// unpack 6 float4 (24 floats) = 8 (x,y,z) triplets into coeff slots [O..O+7]
#define UNPACK8(O, u0, u1, u2, u3, u4, u5)                                    \
    do {                                                                      \
        float qx[8], qy[8], qz[8];                                            \
        qx[0]=u0.x; qy[0]=u0.y; qz[0]=u0.z;                                   \
        qx[1]=u0.w; qy[1]=u1.x; qz[1]=u1.y;                                   \
        qx[2]=u1.z; qy[2]=u1.w; qz[2]=u2.x;                                   \
        qx[3]=u2.y; qy[3]=u2.z; qz[3]=u2.w;                                   \
        qx[4]=u3.x; qy[4]=u3.y; qz[4]=u3.z;                                   \
        qx[5]=u3.w; qy[5]=u4.x; qz[5]=u4.y;                                   \
        qx[6]=u4.z; qy[6]=u4.w; qz[6]=u5.x;                                   \
        qx[7]=u5.y; qy[7]=u5.z; qz[7]=u5.w;                                   \
        _Pragma("unroll")                                                     \
        for (int i = 0; i < 8; ++i) {                                         \
            float ax = -2.0f * qx[i], ay = -2.0f * qy[i], az = -2.0f * qz[i]; \
            ax2[(O) + i] = (v2f){ax, ax};                                     \
            ay2[(O) + i] = (v2f){ay, ay};                                     \
            az2[(O) + i] = (v2f){az, az};                                     \
            mn[(O) + i]  = 3.0e38f;                                           \
        }                                                                     \
    } while (0)

__global__ __launch_bounds__(TPB, 4)   // 4 waves/EU -> 2 blocks/CU, VGPR<=128
void chamfer_main(const float* __restrict__ pred,
                  const float* __restrict__ tgt,
                  float* __restrict__ blkpart /* [NBLK] */)
{
    int bid = blockIdx.x;
    int dir = bid >> 8;               // 0..1
    int b   = (bid >> 5) & 7;         // batch
    int qt  = bid & 31;               // query tile of 128

    const float* qsrc = dir ? tgt  : pred;
    const float* csrc = dir ? pred : tgt;

    __shared__ float4 sbuf[2 * NPAIR];   // 32 KB: pA | pB; reused as scratch
    __shared__ float  acc[TPB / 64];
    float4* pA = sbuf;
    float4* pB = sbuf + NPAIR;

    int tid = threadIdx.x;
    int qg  = tid & (NQG - 1);        // fast index
    int sl  = tid >> 3;               // 64 slices; 8 distinct per wave

    // ---- this thread's 16 consecutive queries: 12 dwordx4, two halves ----
    const float4* q4 = reinterpret_cast<const float4*>(
        qsrc + ((size_t)b * NPTS + (size_t)qt * QB) * 3);
    v2f ax2[QPT], ay2[QPT], az2[QPT];
    float mn[QPT];
    {
        float4 u0 = q4[qg * 12 + 0];
        float4 u1 = q4[qg * 12 + 1];
        float4 u2 = q4[qg * 12 + 2];
        float4 u3 = q4[qg * 12 + 3];
        float4 u4 = q4[qg * 12 + 4];
        float4 u5 = q4[qg * 12 + 5];
        UNPACK8(0, u0, u1, u2, u3, u4, u5);
    }
    {
        float4 u0 = q4[qg * 12 + 6];
        float4 u1 = q4[qg * 12 + 7];
        float4 u2 = q4[qg * 12 + 8];
        float4 u3 = q4[qg * 12 + 9];
        float4 u4 = q4[qg * 12 + 10];
        float4 u5 = q4[qg * 12 + 11];
        UNPACK8(8, u0, u1, u2, u3, u4, u5);
    }

    const float4* t4 = reinterpret_cast<const float4*>(csrc + (size_t)b * NPTS * 3);

    // ---- phase 0 staging: 4 points (2 pairs) per thread, 3 dwordx4 ----
    {
        float4 r0 = t4[tid * 3 + 0];
        float4 r1 = t4[tid * 3 + 1];
        float4 r2 = t4[tid * 3 + 2];
        float w0 = r0.x*r0.x + r0.y*r0.y + r0.z*r0.z;
        float w1 = r0.w*r0.w + r1.x*r1.x + r1.y*r1.y;
        float w2 = r1.z*r1.z + r1.w*r1.w + r2.x*r2.x;
        float w3 = r2.y*r2.y + r2.z*r2.z + r2.w*r2.w;
        pA[tid*2+0] = make_float4(r0.x, r0.w, r0.y, r1.x);
        pB[tid*2+0] = make_float4(r0.z, r1.y, w0, w1);
        pA[tid*2+1] = make_float4(r1.z, r2.y, r1.w, r2.z);
        pB[tid*2+1] = make_float4(r2.x, r2.w, w2, w3);
    }
    __syncthreads();

    {
        const float4* a = pA + sl * SPAIR;
        const float4* c = pB + sl * SPAIR;
        INNER_LOOP(a, c)
    }
    __syncthreads();                   // all reads of phase-0 tiles done

    // ---- phase 1 staging (no reg-prefetch: VGPR budget; TLP hides it) ----
    {
        float4 s0 = t4[1536 + tid * 3 + 0];
        float4 s1 = t4[1536 + tid * 3 + 1];
        float4 s2 = t4[1536 + tid * 3 + 2];
        float w0 = s0.x*s0.x + s0.y*s0.y + s0.z*s0.z;
        float w1 = s0.w*s0.w + s1.x*s1.x + s1.y*s1.y;
        float w2 = s1.z*s1.z + s1.w*s1.w + s2.x*s2.x;
        float w3 = s2.y*s2.y + s2.z*s2.z + s2.w*s2.w;
        pA[tid*2+0] = make_float4(s0.x, s0.w, s0.y, s1.x);
        pB[tid*2+0] = make_float4(s0.z, s1.y, w0, w1);
        pA[tid*2+1] = make_float4(s1.z, s2.y, s1.w, s2.z);
        pB[tid*2+1] = make_float4(s2.x, s2.w, w2, w3);
    }
    __syncthreads();

    {
        const float4* a = pA + sl * SPAIR;
        const float4* c = pB + sl * SPAIR;
        INNER_LOOP(a, c)
    }
    __syncthreads();                   // compute done; sbuf reusable

    // ---- in-block cross-slice reduce: scratch[NSL][QB] = 32 KB ----
    float* scratch = (float*)sbuf;
#pragma unroll
    for (int r = 0; r < QPT; ++r)
        scratch[sl * QB + qg * QPT + r] = mn[r];
    __syncthreads();

    float val = 0.0f;
    if (tid < QB) {                    // one query per thread
        float m = scratch[tid];
#pragma unroll 8
        for (int s = 1; s < NSL; ++s)
            m = fminf(m, scratch[s * QB + tid]);   // lane-contiguous
        const float* qp = qsrc + ((size_t)b * NPTS + (size_t)qt * QB + tid) * 3;
        float x = qp[0], y = qp[1], z = qp[2];     // L1-hot
        val = x*x + y*y + z*z + m;
    }
#pragma unroll
    for (int o = 32; o; o >>= 1) val += __shfl_down(val, o);
    int lane = tid & 63, wid = tid >> 6;
    if (lane == 0) acc[wid] = val;
    __syncthreads();
    if (tid == 0) {
        float s = 0.0f;
#pragma unroll
        for (int i = 0; i < TPB / 64; ++i) s += acc[i];
        blkpart[bid] = s;
    }
}

// node 2: sum 512 block partials, write scalar (plain store, deterministic).
__global__ __launch_bounds__(TPB)
void chamfer_final(const float* __restrict__ blkpart,
                   float* __restrict__ out)
{
    float s = blkpart[threadIdx.x];
#pragma unroll
    for (int o = 32; o; o >>= 1) s += __shfl_down(s, o);
    __shared__ float acc[TPB / 64];
    int lane = threadIdx.x & 63, wid = threadIdx.x >> 6;
    if (lane == 0) acc[wid] = s;
    __syncthreads();
    if (threadIdx.x == 0) {
        float t = 0.0f;
#pragma unroll
        for (int i = 0; i < TPB / 64; ++i) t += acc[i];
        out[0] = t * (1.0f / (BATCH * NPTS));
    }
}

// ---- fallback (no usable ws): block owns 256 queries over full M ----
#define FTPB  256
#define CHUNK 512
#define NCH   (NPTS / CHUNK)

__global__ __launch_bounds__(FTPB)
void chamfer_fallback(const float* __restrict__ pred,
                      const float* __restrict__ tgt,
                      float* __restrict__ out)
{
    int bid = blockIdx.x;
    const int per_dir = BATCH * (NPTS / FTPB);
    int dir = bid / per_dir;
    int r   = bid - dir * per_dir;
    int b   = r / (NPTS / FTPB);
    int qt  = r % (NPTS / FTPB);

    const float* qsrc = dir ? tgt  : pred;
    const float* csrc = dir ? pred : tgt;

    __shared__ float4 sc[CHUNK];
    int q = qt * FTPB + threadIdx.x;
    const float* qp = qsrc + (size_t)(b * NPTS + q) * 3;
    float x = qp[0], y = qp[1], z = qp[2];
    float ax = -2.0f * x, ay = -2.0f * y, az = -2.0f * z;
    float w = x * x + y * y + z * z;
    float mn = 3.0e38f;

    for (int ch = 0; ch < NCH; ++ch) {
        __syncthreads();
        const float* cbase = csrc + (size_t)(b * NPTS + ch * CHUNK) * 3;
        for (int p = threadIdx.x; p < CHUNK; p += FTPB) {
            float tx = cbase[3 * p + 0];
            float ty = cbase[3 * p + 1];
            float tz = cbase[3 * p + 2];
            sc[p] = make_float4(tx, ty, tz, tx * tx + ty * ty + tz * tz);
        }
        __syncthreads();
#pragma unroll 4
        for (int j = 0; j < CHUNK; ++j) {
            float4 t = sc[j];
            float d = fmaf(az, t.z, fmaf(ay, t.y, fmaf(ax, t.x, t.w)));
            mn = fminf(mn, d);
        }
    }
    mn += w;
#pragma unroll
    for (int o = 32; o; o >>= 1) mn += __shfl_down(mn, o);
    __shared__ float acc[FTPB / 64];
    int lane = threadIdx.x & 63, wid = threadIdx.x >> 6;
    if (lane == 0) acc[wid] = mn;
    __syncthreads();
    if (threadIdx.x == 0) {
        float s = 0.0f;
#pragma unroll
        for (int i = 0; i < FTPB / 64; ++i) s += acc[i];
        atomicAdd(out, s * (1.0f / (BATCH * NPTS)));
    }
}

extern "C" void kernel_launch(void* const* d_in, const int* in_sizes, int n_in,
                              void* d_out, int out_size, void* d_ws, size_t ws_size,
                              hipStream_t stream)
{
    const float* pred = (const float*)d_in[0];
    const float* tgt  = (const float*)d_in[1];
    float* out = (float*)d_out;

    if (ws_size >= NBLK * sizeof(float)) {
        float* blkpart = (float*)d_ws;
        chamfer_main<<<NBLK, TPB, 0, stream>>>(pred, tgt, blkpart);
        chamfer_final<<<1, TPB, 0, stream>>>(blkpart, out);
    } else {
        hipMemsetAsync(d_out, 0, sizeof(float), stream);
        chamfer_fallback<<<2 * BATCH * (NPTS / FTPB), FTPB, 0, stream>>>(pred, tgt, out);
    }
}

// Round 11
// 32.574 us; speedup vs baseline: 3.4014x; 3.4014x over previous
//
#include <hip/hip_runtime.h>

// Chamfer loss: pred (8,4096,3) f32, target (8,4096,3) f32 -> scalar f32.
// dist = |q|^2 + (|t|^2 - 2 q.t); inner loop computes min_t(|t|^2 - 2q.t),
// |q|^2 added after the cross-slice min.
//
// Round-11: query-PAIR packing (R10 post-mortem: target-splat packing cost 96
// coeff VGPRs -> spill storm at the 128-reg cap; query-pair packing costs 48).
// Per 2 targets x 16 queries: 8 x (6 v_pk_fma_f32 + 2 v_min3_f32); target
// splats are op_sel-encodable. QPT=16 halves per-wave ds_read issues vs R7;
// slice-rotated LDS reads ((jj+sl)&15) break the stride-512B bank alias;
// reduce scratch padded to stride QB+1. 2-node structure (R9 lesson).

typedef float v2f __attribute__((ext_vector_type(2)));

#define BATCH 8
#define NPTS  4096
#define TPB   512
#define QPT   16                      // queries per thread (consecutive)
#define NQG   8                       // query groups per block
#define QB    (NQG * QPT)             // 128 queries per block
#define NSL   64                      // target slices per block
#define NBLK  (2 * BATCH * (NPTS / QB))  // 512 blocks
#define PHPTS 2048                    // targets staged per phase
#define SLICE (PHPTS / NSL)           // 32 targets per slice per phase
#define SPAIR (SLICE / 2)             // 16 target-pairs per slice per phase
#define RSTR  (QB + 1)                // padded reduce stride (bank spread)

// per target-pair: 2 ds_read_b128 (2-way bank alias = free) +
// 8 query-pairs x (6 pk_fma + 2 min3).
#define INNER_LOOP(BASE)                                                      \
    _Pragma("unroll 4")                                                       \
    for (int jj = 0; jj < SPAIR; ++jj) {                                      \
        int idx = ((jj + sl) & (SPAIR - 1)) * 2;                              \
        float4 t0 = (BASE)[idx];                                              \
        float4 t1 = (BASE)[idx + 1];                                          \
        v2f xx0 = {t0.x, t0.x}, yy0 = {t0.y, t0.y};                           \
        v2f zz0 = {t0.z, t0.z}, ww0 = {t0.w, t0.w};                           \
        v2f xx1 = {t1.x, t1.x}, yy1 = {t1.y, t1.y};                           \
        v2f zz1 = {t1.z, t1.z}, ww1 = {t1.w, t1.w};                           \
        _Pragma("unroll")                                                     \
        for (int i = 0; i < 8; ++i) {                                         \
            v2f da = __builtin_elementwise_fma(azp[i], zz0, ww0);             \
            da = __builtin_elementwise_fma(ayp[i], yy0, da);                  \
            da = __builtin_elementwise_fma(axp[i], xx0, da);                  \
            v2f db = __builtin_elementwise_fma(azp[i], zz1, ww1);             \
            db = __builtin_elementwise_fma(ayp[i], yy1, db);                  \
            db = __builtin_elementwise_fma(axp[i], xx1, db);                  \
            mn[2*i]   = fminf(fminf(da.x, db.x), mn[2*i]);   /* v_min3 */     \
            mn[2*i+1] = fminf(fminf(da.y, db.y), mn[2*i+1]); /* v_min3 */     \
        }                                                                     \
    }

__global__ __launch_bounds__(TPB, 4)   // 4 waves/EU; est ~100 VGPR < 128 cap
void chamfer_main(const float* __restrict__ pred,
                  const float* __restrict__ tgt,
                  float* __restrict__ blkpart /* [NBLK] */)
{
    int bid = blockIdx.x;
    int dir = bid >> 8;               // 0..1
    int b   = (bid >> 5) & 7;         // batch
    int qt  = bid & 31;               // query tile of 128

    const float* qsrc = dir ? tgt  : pred;
    const float* csrc = dir ? pred : tgt;

    // 33 KB union: staging tile (32 KB) / padded reduce scratch (33 KB)
    __shared__ __align__(16) float lds_raw[NSL * RSTR];
    __shared__ float acc[TPB / 64];
    float4* sc = (float4*)lds_raw;          // [PHPTS] float4
    float*  scratch = lds_raw;              // [NSL][RSTR] floats

    int tid = threadIdx.x;
    int qg  = tid & (NQG - 1);        // query group 0..7
    int sl  = tid >> 3;               // slice 0..63

    // ---- 16 consecutive queries: 12 coalesced dwordx4 -> pair coeffs ----
    const float4* q4 = reinterpret_cast<const float4*>(
        qsrc + ((size_t)b * NPTS + (size_t)qt * QB) * 3);
    v2f axp[8], ayp[8], azp[8];
    float mn[QPT];
    {
        float f[48];
#pragma unroll
        for (int k = 0; k < 12; ++k) {
            float4 u = q4[qg * 12 + k];
            f[4*k+0] = u.x; f[4*k+1] = u.y; f[4*k+2] = u.z; f[4*k+3] = u.w;
        }
#pragma unroll
        for (int i = 0; i < 8; ++i) {   // queries 2i, 2i+1
            axp[i] = (v2f){-2.0f * f[6*i+0], -2.0f * f[6*i+3]};
            ayp[i] = (v2f){-2.0f * f[6*i+1], -2.0f * f[6*i+4]};
            azp[i] = (v2f){-2.0f * f[6*i+2], -2.0f * f[6*i+5]};
            mn[2*i] = 3.0e38f; mn[2*i+1] = 3.0e38f;
        }
    }

    const float4* t4 = reinterpret_cast<const float4*>(csrc + (size_t)b * NPTS * 3);

    // ---- phase 0 staging: 4 targets = 3 coalesced dwordx4 per thread ----
    float4 r0 = t4[tid * 3 + 0];
    float4 r1 = t4[tid * 3 + 1];
    float4 r2 = t4[tid * 3 + 2];
    sc[tid*4+0] = make_float4(r0.x, r0.y, r0.z, r0.x*r0.x + r0.y*r0.y + r0.z*r0.z);
    sc[tid*4+1] = make_float4(r0.w, r1.x, r1.y, r0.w*r0.w + r1.x*r1.x + r1.y*r1.y);
    sc[tid*4+2] = make_float4(r1.z, r1.w, r2.x, r1.z*r1.z + r1.w*r1.w + r2.x*r2.x);
    sc[tid*4+3] = make_float4(r2.y, r2.z, r2.w, r2.y*r2.y + r2.z*r2.z + r2.w*r2.w);
    __syncthreads();

    // phase-1 staging loads issued now; latency hides under phase-0 compute
    float4 s0 = t4[1536 + tid * 3 + 0];
    float4 s1 = t4[1536 + tid * 3 + 1];
    float4 s2 = t4[1536 + tid * 3 + 2];

    {
        const float4* base = sc + sl * SLICE;
        INNER_LOOP(base)
    }
    __syncthreads();                   // all reads of phase-0 tile done

    sc[tid*4+0] = make_float4(s0.x, s0.y, s0.z, s0.x*s0.x + s0.y*s0.y + s0.z*s0.z);
    sc[tid*4+1] = make_float4(s0.w, s1.x, s1.y, s0.w*s0.w + s1.x*s1.x + s1.y*s1.y);
    sc[tid*4+2] = make_float4(s1.z, s1.w, s2.x, s1.z*s1.z + s1.w*s1.w + s2.x*s2.x);
    sc[tid*4+3] = make_float4(s2.y, s2.z, s2.w, s2.y*s2.y + s2.z*s2.z + s2.w*s2.w);
    __syncthreads();

    {
        const float4* base = sc + sl * SLICE;
        INNER_LOOP(base)
    }
    __syncthreads();                   // compute done; lds_raw reusable

    // ---- in-block cross-slice reduce (padded stride: ~4-way writes) ----
#pragma unroll
    for (int r = 0; r < QPT; ++r)
        scratch[sl * RSTR + qg * QPT + r] = mn[r];
    __syncthreads();

    float val = 0.0f;
    if (tid < QB) {                    // one query per thread
        float m = scratch[tid];
#pragma unroll 8
        for (int s = 1; s < NSL; ++s)
            m = fminf(m, scratch[s * RSTR + tid]);  // 2-way alias = free
        const float* qp = qsrc + ((size_t)b * NPTS + (size_t)qt * QB + tid) * 3;
        float x = qp[0], y = qp[1], z = qp[2];      // L1/L2-hot
        val = x*x + y*y + z*z + m;
    }
#pragma unroll
    for (int o = 32; o; o >>= 1) val += __shfl_down(val, o);
    int lane = tid & 63, wid = tid >> 6;
    if (lane == 0) acc[wid] = val;
    __syncthreads();
    if (tid == 0) {
        float s = 0.0f;
#pragma unroll
        for (int i = 0; i < TPB / 64; ++i) s += acc[i];
        blkpart[bid] = s;
    }
}

// node 2: sum 512 block partials, write scalar (plain store, deterministic).
__global__ __launch_bounds__(TPB)
void chamfer_final(const float* __restrict__ blkpart,
                   float* __restrict__ out)
{
    float s = blkpart[threadIdx.x];
#pragma unroll
    for (int o = 32; o; o >>= 1) s += __shfl_down(s, o);
    __shared__ float acc[TPB / 64];
    int lane = threadIdx.x & 63, wid = threadIdx.x >> 6;
    if (lane == 0) acc[wid] = s;
    __syncthreads();
    if (threadIdx.x == 0) {
        float t = 0.0f;
#pragma unroll
        for (int i = 0; i < TPB / 64; ++i) t += acc[i];
        out[0] = t * (1.0f / (BATCH * NPTS));
    }
}

// ---- fallback (no usable ws): block owns 256 queries over full M ----
#define FTPB  256
#define CHUNK 512
#define NCH   (NPTS / CHUNK)

__global__ __launch_bounds__(FTPB)
void chamfer_fallback(const float* __restrict__ pred,
                      const float* __restrict__ tgt,
                      float* __restrict__ out)
{
    int bid = blockIdx.x;
    const int per_dir = BATCH * (NPTS / FTPB);
    int dir = bid / per_dir;
    int r   = bid - dir * per_dir;
    int b   = r / (NPTS / FTPB);
    int qt  = r % (NPTS / FTPB);

    const float* qsrc = dir ? tgt  : pred;
    const float* csrc = dir ? pred : tgt;

    __shared__ float4 sc[CHUNK];
    int q = qt * FTPB + threadIdx.x;
    const float* qp = qsrc + (size_t)(b * NPTS + q) * 3;
    float x = qp[0], y = qp[1], z = qp[2];
    float ax = -2.0f * x, ay = -2.0f * y, az = -2.0f * z;
    float w = x * x + y * y + z * z;
    float mn = 3.0e38f;

    for (int ch = 0; ch < NCH; ++ch) {
        __syncthreads();
        const float* cbase = csrc + (size_t)(b * NPTS + ch * CHUNK) * 3;
        for (int p = threadIdx.x; p < CHUNK; p += FTPB) {
            float tx = cbase[3 * p + 0];
            float ty = cbase[3 * p + 1];
            float tz = cbase[3 * p + 2];
            sc[p] = make_float4(tx, ty, tz, tx * tx + ty * ty + tz * tz);
        }
        __syncthreads();
#pragma unroll 4
        for (int j = 0; j < CHUNK; ++j) {
            float4 t = sc[j];
            float d = fmaf(az, t.z, fmaf(ay, t.y, fmaf(ax, t.x, t.w)));
            mn = fminf(mn, d);
        }
    }
    mn += w;
#pragma unroll
    for (int o = 32; o; o >>= 1) mn += __shfl_down(mn, o);
    __shared__ float acc[FTPB / 64];
    int lane = threadIdx.x & 63, wid = threadIdx.x >> 6;
    if (lane == 0) acc[wid] = mn;
    __syncthreads();
    if (threadIdx.x == 0) {
        float s = 0.0f;
#pragma unroll
        for (int i = 0; i < FTPB / 64; ++i) s += acc[i];
        atomicAdd(out, s * (1.0f / (BATCH * NPTS)));
    }
}

extern "C" void kernel_launch(void* const* d_in, const int* in_sizes, int n_in,
                              void* d_out, int out_size, void* d_ws, size_t ws_size,
                              hipStream_t stream)
{
    const float* pred = (const float*)d_in[0];
    const float* tgt  = (const float*)d_in[1];
    float* out = (float*)d_out;

    if (ws_size >= NBLK * sizeof(float)) {
        float* blkpart = (float*)d_ws;
        chamfer_main<<<NBLK, TPB, 0, stream>>>(pred, tgt, blkpart);
        chamfer_final<<<1, TPB, 0, stream>>>(blkpart, out);
    } else {
        hipMemsetAsync(d_out, 0, sizeof(float), stream);
        chamfer_fallback<<<2 * BATCH * (NPTS / FTPB), FTPB, 0, stream>>>(pred, tgt, out);
    }
}

// Round 12
// 28.755 us; speedup vs baseline: 3.8531x; 1.1328x over previous
//
#include <hip/hip_runtime.h>

// Chamfer loss: pred (8,4096,3) f32, target (8,4096,3) f32 -> scalar f32.
// dist = |q|^2 + (|t|^2 - 2 q.t). Inner loop: 3-FMA chain seeded from
// precomputed |t|^2 (LDS); |q|^2 added after the cross-slice min.
// 2 targets/iter -> fminf(fminf(d0,d1),mn) fuses to v_min3_f32.
//
// Round-12: exact R7 champion (28.8 us) + slice-rotated LDS reads.
// R7's slice bases sit at stride 1024 B (all bank 0) -> 4 concurrent slice
// groups per wave = 4-way bank alias (1.58x, m136). Rotation
// idx = ((jj+sl) & 31)*2 puts the 4 groups on banks {0,8,16,24}:
// conflict-free, bijective per slice, order-invariant (min commutes).
// Everything else byte-identical to R7. Evidence from R8/R10/R11: the main
// kernel is NOT issue-bound (VALU -2x was neutral), so this is the last
// pipe-level lever; if neutral, ~29 us is the structural floor
// (staging latency + barriers + ~10 us graph/dispatch overhead).

#define BATCH 8
#define NPTS  4096
#define TPB   512
#define QPT   8                       // queries per thread
#define NQG   16                      // query groups per block
#define QB    (NQG * QPT)             // 128 queries per block
#define NSL   32                      // target slices per block
#define NBLK  (2 * BATCH * (NPTS / QB))  // 512 blocks
#define PHPTS 2048                    // targets staged per phase (32 KB)
#define SLICE (PHPTS / NSL)           // 64 targets per slice per phase

#define INNER_LOOP(SBASE)                                                     \
    _Pragma("unroll 4")                                                       \
    for (int jj = 0; jj < SLICE / 2; ++jj) {                                  \
        int idx = ((jj + sl) & (SLICE / 2 - 1)) * 2;   /* bank-spread */      \
        float4 t0 = (SBASE)[idx];                                             \
        float4 t1 = (SBASE)[idx + 1];                                         \
        _Pragma("unroll")                                                     \
        for (int k = 0; k < QPT; ++k) {                                       \
            float d0 = fmaf(az[k], t0.z, fmaf(ay[k], t0.y, fmaf(ax[k], t0.x, t0.w))); \
            float d1 = fmaf(az[k], t1.z, fmaf(ay[k], t1.y, fmaf(ax[k], t1.x, t1.w))); \
            mn[k] = fminf(fminf(d0, d1), mn[k]);                              \
        }                                                                     \
    }

__global__ __launch_bounds__(TPB, 4)   // 4 waves/EU -> 2 blocks/CU
void chamfer_main(const float* __restrict__ pred,
                  const float* __restrict__ tgt,
                  float* __restrict__ blkpart /* [NBLK] */)
{
    int bid = blockIdx.x;
    int dir = bid >> 8;               // 0..1
    int b   = (bid >> 5) & 7;         // batch
    int qt  = bid & 31;               // query tile of 128

    const float* qsrc = dir ? tgt  : pred;
    const float* csrc = dir ? pred : tgt;

    __shared__ float4 sc[PHPTS];      // 32 KB; reused as reduce scratch later
    __shared__ float  acc[TPB / 64];

    int tid = threadIdx.x;
    int qg  = tid & (NQG - 1);        // fast index -> 4 distinct slices/wave
    int sl  = tid >> 4;

    // ---- this thread's 8 consecutive queries: 6 coalesced dwordx4 ----
    const float4* q4 = reinterpret_cast<const float4*>(
        qsrc + ((size_t)b * NPTS + (size_t)qt * QB) * 3);
    float4 v0 = q4[qg * 6 + 0];
    float4 v1 = q4[qg * 6 + 1];
    float4 v2 = q4[qg * 6 + 2];
    float4 v3 = q4[qg * 6 + 3];
    float4 v4 = q4[qg * 6 + 4];
    float4 v5 = q4[qg * 6 + 5];

    float ax[QPT], ay[QPT], az[QPT], mn[QPT];
    {
        float qx[QPT], qy[QPT], qz[QPT];
        qx[0]=v0.x; qy[0]=v0.y; qz[0]=v0.z;
        qx[1]=v0.w; qy[1]=v1.x; qz[1]=v1.y;
        qx[2]=v1.z; qy[2]=v1.w; qz[2]=v2.x;
        qx[3]=v2.y; qy[3]=v2.z; qz[3]=v2.w;
        qx[4]=v3.x; qy[4]=v3.y; qz[4]=v3.z;
        qx[5]=v3.w; qy[5]=v4.x; qz[5]=v4.y;
        qx[6]=v4.z; qy[6]=v4.w; qz[6]=v5.x;
        qx[7]=v5.y; qy[7]=v5.z; qz[7]=v5.w;
#pragma unroll
        for (int i = 0; i < QPT; ++i) {
            ax[i] = -2.0f * qx[i];
            ay[i] = -2.0f * qy[i];
            az[i] = -2.0f * qz[i];
            mn[i] = 3.0e38f;
        }
    }

    const float4* t4 = reinterpret_cast<const float4*>(csrc + (size_t)b * NPTS * 3);

    // ---- phase 0 staging: 4 points = 3 coalesced dwordx4 per thread ----
    float4 r0 = t4[tid * 3 + 0];
    float4 r1 = t4[tid * 3 + 1];
    float4 r2 = t4[tid * 3 + 2];
    sc[tid*4+0] = make_float4(r0.x, r0.y, r0.z, r0.x*r0.x + r0.y*r0.y + r0.z*r0.z);
    sc[tid*4+1] = make_float4(r0.w, r1.x, r1.y, r0.w*r0.w + r1.x*r1.x + r1.y*r1.y);
    sc[tid*4+2] = make_float4(r1.z, r1.w, r2.x, r1.z*r1.z + r1.w*r1.w + r2.x*r2.x);
    sc[tid*4+3] = make_float4(r2.y, r2.z, r2.w, r2.y*r2.y + r2.z*r2.z + r2.w*r2.w);
    __syncthreads();

    // phase 1 staging loads issued now; latency hides under phase-0 compute
    float4 s0 = t4[1536 + tid * 3 + 0];
    float4 s1 = t4[1536 + tid * 3 + 1];
    float4 s2 = t4[1536 + tid * 3 + 2];

    {
        const float4* sbase = sc + sl * SLICE;
        INNER_LOOP(sbase)
    }
    __syncthreads();                   // all reads of phase-0 sc done

    sc[tid*4+0] = make_float4(s0.x, s0.y, s0.z, s0.x*s0.x + s0.y*s0.y + s0.z*s0.z);
    sc[tid*4+1] = make_float4(s0.w, s1.x, s1.y, s0.w*s0.w + s1.x*s1.x + s1.y*s1.y);
    sc[tid*4+2] = make_float4(s1.z, s1.w, s2.x, s1.z*s1.z + s1.w*s1.w + s2.x*s2.x);
    sc[tid*4+3] = make_float4(s2.y, s2.z, s2.w, s2.y*s2.y + s2.z*s2.z + s2.w*s2.w);
    __syncthreads();

    {
        const float4* sbase = sc + sl * SLICE;
        INNER_LOOP(sbase)
    }
    __syncthreads();                   // compute done; sc reusable as scratch

    // ---- in-block cross-slice reduce ----
    float* scratch = (float*)sc;       // [NSL][QB] floats = 16 KB
#pragma unroll
    for (int r = 0; r < QPT; ++r)
        scratch[sl * QB + qg * QPT + r] = mn[r];
    __syncthreads();

    float val = 0.0f;
    if (tid < QB) {                    // one query per thread
        float m = scratch[tid];
#pragma unroll 8
        for (int s = 1; s < NSL; ++s)
            m = fminf(m, scratch[s * QB + tid]);   // lane-contiguous
        const float* qp = qsrc + ((size_t)b * NPTS + (size_t)qt * QB + tid) * 3;
        float x = qp[0], y = qp[1], z = qp[2];     // L1-hot
        val = x*x + y*y + z*z + m;
    }
#pragma unroll
    for (int o = 32; o; o >>= 1) val += __shfl_down(val, o);
    int lane = tid & 63, wid = tid >> 6;
    if (lane == 0) acc[wid] = val;
    __syncthreads();
    if (tid == 0) {
        float s = 0.0f;
#pragma unroll
        for (int i = 0; i < TPB / 64; ++i) s += acc[i];
        blkpart[bid] = s;
    }
}

// node 2: sum 512 block partials, write scalar (plain store, deterministic).
__global__ __launch_bounds__(TPB)
void chamfer_final(const float* __restrict__ blkpart,
                   float* __restrict__ out)
{
    float s = blkpart[threadIdx.x];
#pragma unroll
    for (int o = 32; o; o >>= 1) s += __shfl_down(s, o);
    __shared__ float acc[TPB / 64];
    int lane = threadIdx.x & 63, wid = threadIdx.x >> 6;
    if (lane == 0) acc[wid] = s;
    __syncthreads();
    if (threadIdx.x == 0) {
        float t = 0.0f;
#pragma unroll
        for (int i = 0; i < TPB / 64; ++i) t += acc[i];
        out[0] = t * (1.0f / (BATCH * NPTS));
    }
}

// ---- fallback (no usable ws): block owns 256 queries over full M ----
#define FTPB  256
#define CHUNK 512
#define NCH   (NPTS / CHUNK)

__global__ __launch_bounds__(FTPB)
void chamfer_fallback(const float* __restrict__ pred,
                      const float* __restrict__ tgt,
                      float* __restrict__ out)
{
    int bid = blockIdx.x;
    const int per_dir = BATCH * (NPTS / FTPB);
    int dir = bid / per_dir;
    int r   = bid - dir * per_dir;
    int b   = r / (NPTS / FTPB);
    int qt  = r % (NPTS / FTPB);

    const float* qsrc = dir ? tgt  : pred;
    const float* csrc = dir ? pred : tgt;

    __shared__ float4 sc[CHUNK];
    int q = qt * FTPB + threadIdx.x;
    const float* qp = qsrc + (size_t)(b * NPTS + q) * 3;
    float x = qp[0], y = qp[1], z = qp[2];
    float ax = -2.0f * x, ay = -2.0f * y, az = -2.0f * z;
    float w = x * x + y * y + z * z;
    float mn = 3.0e38f;

    for (int ch = 0; ch < NCH; ++ch) {
        __syncthreads();
        const float* cbase = csrc + (size_t)(b * NPTS + ch * CHUNK) * 3;
        for (int p = threadIdx.x; p < CHUNK; p += FTPB) {
            float tx = cbase[3 * p + 0];
            float ty = cbase[3 * p + 1];
            float tz = cbase[3 * p + 2];
            sc[p] = make_float4(tx, ty, tz, tx * tx + ty * ty + tz * tz);
        }
        __syncthreads();
#pragma unroll 4
        for (int j = 0; j < CHUNK; ++j) {
            float4 t = sc[j];
            float d = fmaf(az, t.z, fmaf(ay, t.y, fmaf(ax, t.x, t.w)));
            mn = fminf(mn, d);
        }
    }
    mn += w;
#pragma unroll
    for (int o = 32; o; o >>= 1) mn += __shfl_down(mn, o);
    __shared__ float acc[FTPB / 64];
    int lane = threadIdx.x & 63, wid = threadIdx.x >> 6;
    if (lane == 0) acc[wid] = mn;
    __syncthreads();
    if (threadIdx.x == 0) {
        float s = 0.0f;
#pragma unroll
        for (int i = 0; i < FTPB / 64; ++i) s += acc[i];
        atomicAdd(out, s * (1.0f / (BATCH * NPTS)));
    }
}

extern "C" void kernel_launch(void* const* d_in, const int* in_sizes, int n_in,
                              void* d_out, int out_size, void* d_ws, size_t ws_size,
                              hipStream_t stream)
{
    const float* pred = (const float*)d_in[0];
    const float* tgt  = (const float*)d_in[1];
    float* out = (float*)d_out;

    if (ws_size >= NBLK * sizeof(float)) {
        float* blkpart = (float*)d_ws;
        chamfer_main<<<NBLK, TPB, 0, stream>>>(pred, tgt, blkpart);
        chamfer_final<<<1, TPB, 0, stream>>>(blkpart, out);
    } else {
        hipMemsetAsync(d_out, 0, sizeof(float), stream);
        chamfer_fallback<<<2 * BATCH * (NPTS / FTPB), FTPB, 0, stream>>>(pred, tgt, out);
    }
}